// Round 4
// baseline (1449.250 us; speedup 1.0000x reference)
//
#include <hip/hip_runtime.h>

// NeuralBPDecoder: sparse BP over a 0.1%-dense parity matrix.
// Structure (round 4): batch lanes are independent -> one block per batch
// lane holds that lane's ENTIRE BP state in LDS (beliefs 64KB + cmsg 32KB)
// and runs all 15 iterations with __syncthreads() between phases. This
// removes the 30 phase dispatches (~310us of launch overhead, round 3) and
// the 45us/sync cooperative barriers (round 2). 3 dispatches total.
// Index tables are u16 CSR built from one 512MB H scan (the HBM floor).

#define C_NUM 8192
#define V_NUM 16384
#define B_NUM 32
#define RW 64   // u16 slots per check row (mean nnz 16.4; tail << 64)
#define CW 32   // u16 slots per var col  (mean nnz  8.2; tail << 32)

typedef unsigned short u16;
typedef unsigned int u32;

__global__ void build_csr(const float* __restrict__ H,
                          int* __restrict__ row_cnt, int* __restrict__ col_cnt,
                          u16* __restrict__ row_idx, u16* __restrict__ col_idx) {
    const int tid = blockIdx.x * blockDim.x + threadIdx.x;
    const int nth = gridDim.x * blockDim.x;
    const int total4 = C_NUM * V_NUM / 4;
    for (int t = tid; t < total4; t += nth) {
        float4 hv = ((const float4*)H)[t];
        int e = t * 4;
        float vals[4] = {hv.x, hv.y, hv.z, hv.w};
#pragma unroll
        for (int k = 0; k < 4; ++k) {
            if (vals[k] != 0.0f) {
                int ee = e + k;
                int c = ee >> 14;            // V = 2^14
                int v = ee & (V_NUM - 1);
                int rs = atomicAdd(&row_cnt[c], 1);
                if (rs < RW) row_idx[c * RW + rs] = (u16)v;
                int cs = atomicAdd(&col_cnt[v], 1);
                if (cs < CW) col_idx[v * CW + cs] = (u16)c;
            }
        }
    }
}

__device__ __forceinline__ float fast_tanh_half(float x) {
    // tanh(x/2) = sign(x) * (1 - e^-|x|) / (1 + e^-|x|)
    float ax = fabsf(x);
    float e = __expf(-ax);
    return copysignf((1.0f - e) / (1.0f + e), x);
}

__global__ __launch_bounds__(1024, 4)
void bp_solve(const float* __restrict__ synd,   // (B, C)
              const float* __restrict__ llr,    // (B, V)
              const float* __restrict__ w_vc_p,
              const float* __restrict__ w_cv_p,
              const float* __restrict__ damp_p,
              const int* __restrict__ row_cnt, const int* __restrict__ col_cnt,
              const u16* __restrict__ row_idx, const u16* __restrict__ col_idx,
              float* __restrict__ out) {      // (B, V)
    __shared__ float bel[V_NUM];   // 64 KB
    __shared__ float cms[C_NUM];   // 32 KB
    const int b   = blockIdx.x;    // batch lane
    const int tid = threadIdx.x;   // 1024 threads: 16 vars + 8 checks each

    // ---- load this lane's state; cache per-thread constants in VGPRs ----
    float llr_r[16]; int ncol[16];
#pragma unroll
    for (int k = 0; k < 16; ++k) {
        int v = tid + (k << 10);
        float x = llr[b * V_NUM + v];
        llr_r[k] = x;
        bel[v] = x;
        int n = col_cnt[v];
        ncol[k] = n > CW ? CW : n;
    }
    float ss[8]; int nrow[8];
#pragma unroll
    for (int k = 0; k < 8; ++k) {
        int c = tid + (k << 10);
        ss[k] = 1.0f - 2.0f * synd[b * C_NUM + c];
        int n = row_cnt[c];
        nrow[k] = n > RW ? RW : n;
    }
    const float wvc = w_vc_p[0];
    const float wcv = w_cv_p[0];
    const float d   = damp_p[0];
    __syncthreads();

    // ---- 15 BP iterations, all block-local ----
    for (int it = 0; it < 15; ++it) {
        // v->c : cms[c] = ss * tanh(0.5 * wvc * sum bel[row])
#pragma unroll
        for (int k = 0; k < 8; ++k) {
            int c = tid + (k << 10);
            int n = nrow[k];
            const uint4* q8 = (const uint4*)&row_idx[c * RW];  // 8 u16 / uint4
            float sum = 0.0f;
            int full = n >> 3, p = 0;
            for (; p < full; ++p) {
                uint4 q = q8[p];
                sum += bel[q.x & 0xFFFFu] + bel[q.x >> 16]
                     + bel[q.y & 0xFFFFu] + bel[q.y >> 16]
                     + bel[q.z & 0xFFFFu] + bel[q.z >> 16]
                     + bel[q.w & 0xFFFFu] + bel[q.w >> 16];
            }
            int rem = n & 7;
            if (rem) {                      // tail slots are zero-filled -> bel[0], guarded
                uint4 q = q8[p];
                sum += bel[q.x & 0xFFFFu];
                sum += (rem > 1) ? bel[q.x >> 16]     : 0.0f;
                sum += (rem > 2) ? bel[q.y & 0xFFFFu] : 0.0f;
                sum += (rem > 3) ? bel[q.y >> 16]     : 0.0f;
                sum += (rem > 4) ? bel[q.z & 0xFFFFu] : 0.0f;
                sum += (rem > 5) ? bel[q.z >> 16]     : 0.0f;
                sum += (rem > 6) ? bel[q.w & 0xFFFFu] : 0.0f;
            }
            cms[c] = ss[k] * fast_tanh_half(wvc * sum);
        }
        __syncthreads();
        // c->v : bel[v] = d*bel[v] + (1-d)*(llr + wcv * sum cms[col])
#pragma unroll
        for (int k = 0; k < 16; ++k) {
            int v = tid + (k << 10);
            int n = ncol[k];
            const uint4* q8 = (const uint4*)&col_idx[v * CW];
            float sum = 0.0f;
            int full = n >> 3, p = 0;
            for (; p < full; ++p) {
                uint4 q = q8[p];
                sum += cms[q.x & 0xFFFFu] + cms[q.x >> 16]
                     + cms[q.y & 0xFFFFu] + cms[q.y >> 16]
                     + cms[q.z & 0xFFFFu] + cms[q.z >> 16]
                     + cms[q.w & 0xFFFFu] + cms[q.w >> 16];
            }
            int rem = n & 7;
            if (rem) {
                uint4 q = q8[p];
                sum += cms[q.x & 0xFFFFu];
                sum += (rem > 1) ? cms[q.x >> 16]     : 0.0f;
                sum += (rem > 2) ? cms[q.y & 0xFFFFu] : 0.0f;
                sum += (rem > 3) ? cms[q.y >> 16]     : 0.0f;
                sum += (rem > 4) ? cms[q.z & 0xFFFFu] : 0.0f;
                sum += (rem > 5) ? cms[q.z >> 16]     : 0.0f;
                sum += (rem > 6) ? cms[q.w & 0xFFFFu] : 0.0f;
            }
            bel[v] = d * bel[v] + (1.0f - d) * (llr_r[k] + wcv * sum);
        }
        __syncthreads();
    }

    // ---- epilogue: out[b,v] = sigmoid(-bel[v]) ----
#pragma unroll
    for (int k = 0; k < 16; ++k) {
        int v = tid + (k << 10);
        out[b * V_NUM + v] = 1.0f / (1.0f + __expf(bel[v]));
    }
}

extern "C" void kernel_launch(void* const* d_in, const int* in_sizes, int n_in,
                              void* d_out, int out_size, void* d_ws, size_t ws_size,
                              hipStream_t stream) {
    const float* synd = (const float*)d_in[0];   // (B, C)
    const float* H    = (const float*)d_in[1];   // (C, V)
    const float* llr  = (const float*)d_in[2];   // (B, V)
    const float* w_vc = (const float*)d_in[3];
    const float* w_cv = (const float*)d_in[4];
    const float* damp = (const float*)d_in[5];
    float* out = (float*)d_out;

    // ws layout: counters + u16 idx tables contiguous -> single zeroing memset
    char* ws = (char*)d_ws;
    size_t off = 0;
    int* row_cnt = (int*)(ws + off); off += (size_t)C_NUM * 4;            // 32 KB
    int* col_cnt = (int*)(ws + off); off += (size_t)V_NUM * 4;            // 64 KB
    u16* row_idx = (u16*)(ws + off); off += (size_t)C_NUM * RW * 2;       // 1 MB
    u16* col_idx = (u16*)(ws + off); off += (size_t)V_NUM * CW * 2;       // 1 MB
    size_t zero_bytes = off;

    hipMemsetAsync(ws, 0, zero_bytes, stream);

    build_csr<<<8192, 256, 0, stream>>>(H, row_cnt, col_cnt, row_idx, col_idx);

    bp_solve<<<B_NUM, 1024, 0, stream>>>(synd, llr, w_vc, w_cv, damp,
                                         row_cnt, col_cnt, row_idx, col_idx, out);
}